// Round 1
// baseline (830.627 us; speedup 1.0000x reference)
//
#include <hip/hip_runtime.h>
#include <math.h>

// ---------------------------------------------------------------------------
// GNN pool: 2x GCNConv(elu) + MLP(128) + Linear(15) + softmax
// N=100000, E=3200000, IN=3, HID=64, MLP_HID=128, K=15, all fp32.
//
// Pipeline (all on `stream`):
//   memset deg,cursor -> deg count (atomics) -> dis/sx -> scan(3) -> CSR fill
//   -> agg3+W1+elu (wave/node, lane-parallel over nbrs, 3 feats)
//   -> agg64 (wave/node, lane=feature, 4-wide edge unroll)
//   -> headA: a2 @ W2 (elu) @ Wm1 (elu) -> m [N,128]   (LDS-tiled, 16 nodes)
//   -> headB: m @ Wm2 + softmax -> out [N,15]
// ---------------------------------------------------------------------------

#define NT  16   // nodes per head tile
#define NTP 17   // padded leading dim for [*][NT] LDS tiles

__global__ void deg_kernel(const int* __restrict__ dst, int* __restrict__ deg, int E) {
    int e = blockIdx.x * blockDim.x + threadIdx.x;
    if (e < E) atomicAdd(&deg[dst[e]], 1);
}

__global__ void dis_kernel(const int* __restrict__ deg, const float* __restrict__ x,
                           float* __restrict__ dis, float* __restrict__ sx, int N) {
    int i = blockIdx.x * blockDim.x + threadIdx.x;
    if (i < N) {
        float r = rsqrtf((float)(deg[i] + 1));  // +1 self loop; always >=1
        dis[i] = r;
        sx[i * 3 + 0] = r * x[i * 3 + 0];
        sx[i * 3 + 1] = r * x[i * 3 + 1];
        sx[i * 3 + 2] = r * x[i * 3 + 2];
    }
}

// ---- exclusive scan of deg -> row_ptr (chunk = 2048/block) ----
__global__ void scan1_kernel(const int* __restrict__ deg, int* __restrict__ bsum, int N) {
    __shared__ int ls[256];
    int t = threadIdx.x, b = blockIdx.x;
    int base = b * 2048 + t * 8;
    int s = 0;
    for (int j = 0; j < 8; ++j) { int idx = base + j; if (idx < N) s += deg[idx]; }
    ls[t] = s; __syncthreads();
    for (int off = 128; off; off >>= 1) {
        if (t < off) ls[t] += ls[t + off];
        __syncthreads();
    }
    if (t == 0) bsum[b] = ls[0];
}

__global__ void scan2_kernel(int* __restrict__ bsum, int* __restrict__ row_ptr, int NB, int N) {
    if (blockIdx.x == 0 && threadIdx.x == 0) {
        int run = 0;
        for (int b = 0; b < NB; ++b) { int v = bsum[b]; bsum[b] = run; run += v; }
        row_ptr[N] = run;
    }
}

__global__ void scan3_kernel(const int* __restrict__ deg, const int* __restrict__ bsum,
                             int* __restrict__ row_ptr, int N) {
    __shared__ int ls[256];
    int t = threadIdx.x, b = blockIdx.x;
    int base = b * 2048 + t * 8;
    int v[8]; int s = 0;
    for (int j = 0; j < 8; ++j) { int idx = base + j; v[j] = (idx < N) ? deg[idx] : 0; s += v[j]; }
    ls[t] = s; __syncthreads();
    for (int off = 1; off < 256; off <<= 1) {
        int xv = (t >= off) ? ls[t - off] : 0;
        __syncthreads();
        ls[t] += xv;
        __syncthreads();
    }
    int excl = ls[t] - s + bsum[b];
    for (int j = 0; j < 8; ++j) { int idx = base + j; if (idx < N) row_ptr[idx] = excl; excl += v[j]; }
}

__global__ void fill_kernel(const int* __restrict__ src, const int* __restrict__ dst,
                            const int* __restrict__ row_ptr, int* __restrict__ cursor,
                            int* __restrict__ col, int E) {
    int e = blockIdx.x * blockDim.x + threadIdx.x;
    if (e < E) {
        int d = dst[e];
        int pos = row_ptr[d] + atomicAdd(&cursor[d], 1);
        col[pos] = src[e];
    }
}

// ---- layer 1: aggregate sx (3 feats) + W1 transform + bias + elu; write s1=dis*h1 ----
__global__ void agg3_kernel(const float* __restrict__ sx, const int* __restrict__ row_ptr,
                            const int* __restrict__ col, const float* __restrict__ dis,
                            const float* __restrict__ W1, const float* __restrict__ b1,
                            float* __restrict__ s1, int N) {
    int wave = (blockIdx.x * blockDim.x + threadIdx.x) >> 6;
    int lane = threadIdx.x & 63;
    if (wave >= N) return;
    int d = wave;
    int start = row_ptr[d], end = row_ptr[d + 1];
    float a0 = 0.f, a1 = 0.f, a2v = 0.f;
    for (int i = start + lane; i < end; i += 64) {
        int s = col[i];
        a0  += sx[s * 3 + 0];
        a1  += sx[s * 3 + 1];
        a2v += sx[s * 3 + 2];
    }
#pragma unroll
    for (int off = 32; off; off >>= 1) {
        a0  += __shfl_xor(a0, off);
        a1  += __shfl_xor(a1, off);
        a2v += __shfl_xor(a2v, off);
    }
    // self loop
    a0  += sx[d * 3 + 0];
    a1  += sx[d * 3 + 1];
    a2v += sx[d * 3 + 2];
    float r = dis[d];
    float v = r * (a0 * W1[lane] + a1 * W1[64 + lane] + a2v * W1[128 + lane]) + b1[lane];
    v = (v > 0.f) ? v : expm1f(v);
    s1[(size_t)d * 64 + lane] = r * v;  // pre-scale for next aggregation
}

// ---- layer 2 aggregation: a2[d] = dis[d]*(sum_nbr s1[s] + s1[d]) ----
__global__ void agg64_kernel(const float* __restrict__ s1, const int* __restrict__ row_ptr,
                             const int* __restrict__ col, const float* __restrict__ dis,
                             float* __restrict__ a2, int N) {
    int wave = (blockIdx.x * blockDim.x + threadIdx.x) >> 6;
    int lane = threadIdx.x & 63;
    if (wave >= N) return;
    int d = wave;
    int start = row_ptr[d], end = row_ptr[d + 1];
    float acc0 = s1[(size_t)d * 64 + lane];  // self loop
    float acc1 = 0.f, acc2 = 0.f, acc3 = 0.f;
    int i = start;
    for (; i + 3 < end; i += 4) {
        int s0 = col[i], s1i = col[i + 1], s2 = col[i + 2], s3 = col[i + 3];
        acc0 += s1[(size_t)s0  * 64 + lane];
        acc1 += s1[(size_t)s1i * 64 + lane];
        acc2 += s1[(size_t)s2  * 64 + lane];
        acc3 += s1[(size_t)s3  * 64 + lane];
    }
    for (; i < end; ++i) acc0 += s1[(size_t)col[i] * 64 + lane];
    a2[(size_t)d * 64 + lane] = dis[d] * ((acc0 + acc1) + (acc2 + acc3));
}

// ---- head A: h2 = elu(a2@W2+b2); m = elu(h2@Wm1+bm1) ----
__global__ __launch_bounds__(256) void headA_kernel(const float* __restrict__ a2,
    const float* __restrict__ W2g, const float* __restrict__ b2g,
    const float* __restrict__ Wm1g, const float* __restrict__ bm1g,
    float* __restrict__ m, int N) {
    __shared__ float W2[64 * 64];
    __shared__ float Wm1[64 * 128];
    __shared__ float b2s[64];
    __shared__ float bm1s[128];
    __shared__ float at[64 * NTP];  // a2 transposed [k][n]
    __shared__ float tt[64 * NTP];  // h2 [f][n]
    int tid = threadIdx.x;
    for (int i = tid; i < 64 * 64;  i += 256) W2[i]  = W2g[i];
    for (int i = tid; i < 64 * 128; i += 256) Wm1[i] = Wm1g[i];
    if (tid < 64)  b2s[tid]  = b2g[tid];
    if (tid < 128) bm1s[tid] = bm1g[tid];
    __syncthreads();
    int nTiles = (N + NT - 1) / NT;
    for (int tile = blockIdx.x; tile < nTiles; tile += gridDim.x) {
        int base = tile * NT;
        {   // stage a2 tile transposed (coalesced read, pad-17 conflict-free write)
            int n = tid >> 6, k = tid & 63;
#pragma unroll
            for (int g = 0; g < 4; ++g) {
                int nn = n + g * 4;
                int node = base + nn; if (node >= N) node = N - 1;
                at[k * NTP + nn] = a2[(size_t)node * 64 + k];
            }
        }
        __syncthreads();
        {   // stage A: 64 outputs x 16 nodes; thread = (f, 4-node group)
            int f = tid & 63, n0 = (tid >> 6) * 4;
            float bb = b2s[f];
            float acc[4] = {bb, bb, bb, bb};
            for (int k = 0; k < 64; ++k) {
                float w = W2[k * 64 + f];
#pragma unroll
                for (int i = 0; i < 4; ++i) acc[i] = fmaf(w, at[k * NTP + n0 + i], acc[i]);
            }
#pragma unroll
            for (int i = 0; i < 4; ++i) {
                float v = acc[i];
                tt[f * NTP + n0 + i] = (v > 0.f) ? v : expm1f(v);
            }
        }
        __syncthreads();
        {   // stage B: 128 outputs x 16 nodes; thread = (j, 8-node group)
            int j = tid & 127, n0 = (tid >> 7) * 8;
            float bb = bm1s[j];
            float acc[8];
#pragma unroll
            for (int i = 0; i < 8; ++i) acc[i] = bb;
            for (int f = 0; f < 64; ++f) {
                float w = Wm1[f * 128 + j];
#pragma unroll
                for (int i = 0; i < 8; ++i) acc[i] = fmaf(w, tt[f * NTP + n0 + i], acc[i]);
            }
#pragma unroll
            for (int i = 0; i < 8; ++i) {
                float v = acc[i];
                v = (v > 0.f) ? v : expm1f(v);
                int node = base + n0 + i;
                if (node < N) m[(size_t)node * 128 + j] = v;
            }
        }
        __syncthreads();
    }
}

// ---- head B: out = softmax(m@Wm2+bm2) ----
__global__ __launch_bounds__(256) void headB_kernel(const float* __restrict__ m,
    const float* __restrict__ Wm2g, const float* __restrict__ bm2g,
    float* __restrict__ out, int N) {
    __shared__ float Wm2[128 * 16];   // padded K dim 15->16
    __shared__ float bm2s[16];
    __shared__ float mt[NT * 129];    // [n][j] padded
    __shared__ float ot[NT * 16];
    int tid = threadIdx.x;
    for (int i = tid; i < 128 * 16; i += 256) {
        int j = i >> 4, c = i & 15;
        Wm2[i] = (c < 15) ? Wm2g[j * 15 + c] : 0.f;
    }
    if (tid < 16) bm2s[tid] = (tid < 15) ? bm2g[tid] : 0.f;
    __syncthreads();
    int nTiles = (N + NT - 1) / NT;
    int n = tid / 15, c = tid % 15;
    bool act = (tid < 240);
    for (int tile = blockIdx.x; tile < nTiles; tile += gridDim.x) {
        int base = tile * NT;
        for (int i = tid; i < NT * 128; i += 256) {
            int n2 = i >> 7, j = i & 127;
            int node = base + n2;
            mt[n2 * 129 + j] = (node < N) ? m[(size_t)node * 128 + j] : 0.f;
        }
        __syncthreads();
        if (act) {
            float acc = bm2s[c];
            for (int j = 0; j < 128; ++j) acc = fmaf(mt[n * 129 + j], Wm2[j * 16 + c], acc);
            ot[n * 16 + c] = acc;
        }
        __syncthreads();
        if (act) {
            float mx = -1e30f;
            for (int cc = 0; cc < 15; ++cc) mx = fmaxf(mx, ot[n * 16 + cc]);
            float ssum = 0.f;
            for (int cc = 0; cc < 15; ++cc) ssum += __expf(ot[n * 16 + cc] - mx);
            int node = base + n;
            if (node < N) out[(size_t)node * 15 + c] = __expf(ot[n * 16 + c] - mx) / ssum;
        }
        __syncthreads();
    }
}

extern "C" void kernel_launch(void* const* d_in, const int* in_sizes, int n_in,
                              void* d_out, int out_size, void* d_ws, size_t ws_size,
                              hipStream_t stream) {
    const float* x   = (const float*)d_in[0];
    const int*   ei  = (const int*)d_in[1];
    const float* W1  = (const float*)d_in[2];
    const float* b1  = (const float*)d_in[3];
    const float* W2  = (const float*)d_in[4];
    const float* b2  = (const float*)d_in[5];
    const float* Wm1 = (const float*)d_in[6];
    const float* bm1 = (const float*)d_in[7];
    const float* Wm2 = (const float*)d_in[8];
    const float* bm2 = (const float*)d_in[9];
    float* out = (float*)d_out;

    int N = in_sizes[0] / 3;
    int E = in_sizes[1] / 2;
    const int* src = ei;
    const int* dst = ei + E;

    // ---- workspace carve (a2 first; everything else dead by headA -> m aliases it) ----
    uintptr_t p = (uintptr_t)d_ws;
    auto carve = [&](size_t bytes) -> void* {
        p = (p + 255) & ~(uintptr_t)255;
        void* r = (void*)p;
        p += bytes;
        return r;
    };
    float* a2 = (float*)carve((size_t)N * 64 * 4);
    uintptr_t reuse_start = (p + 255) & ~(uintptr_t)255;
    float* m = (float*)reuse_start;            // N*128*4, overlays the CSR/temp region
    uintptr_t q = reuse_start;
    auto carve2 = [&](size_t bytes) -> void* {
        q = (q + 255) & ~(uintptr_t)255;
        void* r = (void*)q;
        q += bytes;
        return r;
    };
    int*   deg     = (int*)carve2((size_t)N * 4);
    int*   cursor  = (int*)carve2((size_t)N * 4);
    int*   row_ptr = (int*)carve2((size_t)(N + 1) * 4);
    int*   bsum    = (int*)carve2(256);
    float* dis     = (float*)carve2((size_t)N * 4);
    float* sx      = (float*)carve2((size_t)N * 12);
    int*   col     = (int*)carve2((size_t)E * 4);
    float* s1      = (float*)carve2((size_t)N * 64 * 4);

    int eBlocks = (E + 255) / 256;
    int nBlocks = (N + 255) / 256;
    int NB = (N + 2047) / 2048;
    int waveBlocks = (N + 3) / 4;  // 4 waves (nodes) per 256-thread block

    hipMemsetAsync(deg,    0, (size_t)N * 4, stream);
    hipMemsetAsync(cursor, 0, (size_t)N * 4, stream);

    deg_kernel<<<eBlocks, 256, 0, stream>>>(dst, deg, E);
    dis_kernel<<<nBlocks, 256, 0, stream>>>(deg, x, dis, sx, N);
    scan1_kernel<<<NB, 256, 0, stream>>>(deg, bsum, N);
    scan2_kernel<<<1, 64, 0, stream>>>(bsum, row_ptr, NB, N);
    scan3_kernel<<<NB, 256, 0, stream>>>(deg, bsum, row_ptr, N);
    fill_kernel<<<eBlocks, 256, 0, stream>>>(src, dst, row_ptr, cursor, col, E);
    agg3_kernel<<<waveBlocks, 256, 0, stream>>>(sx, row_ptr, col, dis, W1, b1, s1, N);
    agg64_kernel<<<waveBlocks, 256, 0, stream>>>(s1, row_ptr, col, dis, a2, N);
    headA_kernel<<<1024, 256, 0, stream>>>(a2, W2, b2, Wm1, bm1, m, N);
    headB_kernel<<<1024, 256, 0, stream>>>(m, Wm2, bm2, out, N);
}

// Round 2
// 736.731 us; speedup vs baseline: 1.1274x; 1.1274x over previous
//
#include <hip/hip_runtime.h>
#include <math.h>

// ---------------------------------------------------------------------------
// GNN pool: 2x GCNConv(elu) + MLP(128) + Linear(15) + softmax
// N=100000, E=3200000, IN=3, HID=64, MLP_HID=128, K=15, all fp32.
//
// Pipeline:
//   memset deg,cursor -> deg count -> dis/sx -> scan(3) -> CSR fill
//   -> agg3+W1+elu (wave/node, 3 feats)
//   -> agg64 (wave/node, lane=feature)
//   -> head: a2@W2 elu @Wm1 elu @Wm2 softmax -> out   (single fused kernel,
//      16-node LDS tiles, acc[4] max per thread, unroll-4 to avoid the
//      register-spill catastrophe seen in round 1's headA: VGPR=256 + 75 GB
//      scratch traffic + VALUBusy 2.7%)
// ---------------------------------------------------------------------------

#define NT  16   // nodes per head tile
#define NTP 17   // padded leading dim for [*][NT] LDS tiles

__global__ void deg_kernel(const int* __restrict__ dst, int* __restrict__ deg, int E) {
    int e = blockIdx.x * blockDim.x + threadIdx.x;
    if (e < E) atomicAdd(&deg[dst[e]], 1);
}

__global__ void dis_kernel(const int* __restrict__ deg, const float* __restrict__ x,
                           float* __restrict__ dis, float* __restrict__ sx, int N) {
    int i = blockIdx.x * blockDim.x + threadIdx.x;
    if (i < N) {
        float r = rsqrtf((float)(deg[i] + 1));  // +1 self loop; always >=1
        dis[i] = r;
        sx[i * 3 + 0] = r * x[i * 3 + 0];
        sx[i * 3 + 1] = r * x[i * 3 + 1];
        sx[i * 3 + 2] = r * x[i * 3 + 2];
    }
}

// ---- exclusive scan of deg -> row_ptr (chunk = 2048/block) ----
__global__ void scan1_kernel(const int* __restrict__ deg, int* __restrict__ bsum, int N) {
    __shared__ int ls[256];
    int t = threadIdx.x, b = blockIdx.x;
    int base = b * 2048 + t * 8;
    int s = 0;
    for (int j = 0; j < 8; ++j) { int idx = base + j; if (idx < N) s += deg[idx]; }
    ls[t] = s; __syncthreads();
    for (int off = 128; off; off >>= 1) {
        if (t < off) ls[t] += ls[t + off];
        __syncthreads();
    }
    if (t == 0) bsum[b] = ls[0];
}

__global__ void scan2_kernel(int* __restrict__ bsum, int* __restrict__ row_ptr, int NB, int N) {
    if (blockIdx.x == 0 && threadIdx.x == 0) {
        int run = 0;
        for (int b = 0; b < NB; ++b) { int v = bsum[b]; bsum[b] = run; run += v; }
        row_ptr[N] = run;
    }
}

__global__ void scan3_kernel(const int* __restrict__ deg, const int* __restrict__ bsum,
                             int* __restrict__ row_ptr, int N) {
    __shared__ int ls[256];
    int t = threadIdx.x, b = blockIdx.x;
    int base = b * 2048 + t * 8;
    int v[8]; int s = 0;
    for (int j = 0; j < 8; ++j) { int idx = base + j; v[j] = (idx < N) ? deg[idx] : 0; s += v[j]; }
    ls[t] = s; __syncthreads();
    for (int off = 1; off < 256; off <<= 1) {
        int xv = (t >= off) ? ls[t - off] : 0;
        __syncthreads();
        ls[t] += xv;
        __syncthreads();
    }
    int excl = ls[t] - s + bsum[b];
    for (int j = 0; j < 8; ++j) { int idx = base + j; if (idx < N) row_ptr[idx] = excl; excl += v[j]; }
}

__global__ void fill_kernel(const int* __restrict__ src, const int* __restrict__ dst,
                            const int* __restrict__ row_ptr, int* __restrict__ cursor,
                            int* __restrict__ col, int E) {
    int e = blockIdx.x * blockDim.x + threadIdx.x;
    if (e < E) {
        int d = dst[e];
        int pos = row_ptr[d] + atomicAdd(&cursor[d], 1);
        col[pos] = src[e];
    }
}

// ---- layer 1: aggregate sx (3 feats) + W1 transform + bias + elu; write s1=dis*h1 ----
__global__ void agg3_kernel(const float* __restrict__ sx, const int* __restrict__ row_ptr,
                            const int* __restrict__ col, const float* __restrict__ dis,
                            const float* __restrict__ W1, const float* __restrict__ b1,
                            float* __restrict__ s1, int N) {
    int wave = (blockIdx.x * blockDim.x + threadIdx.x) >> 6;
    int lane = threadIdx.x & 63;
    if (wave >= N) return;
    int d = wave;
    int start = row_ptr[d], end = row_ptr[d + 1];
    float a0 = 0.f, a1 = 0.f, a2v = 0.f;
    for (int i = start + lane; i < end; i += 64) {
        int s = col[i];
        a0  += sx[s * 3 + 0];
        a1  += sx[s * 3 + 1];
        a2v += sx[s * 3 + 2];
    }
#pragma unroll
    for (int off = 32; off; off >>= 1) {
        a0  += __shfl_xor(a0, off);
        a1  += __shfl_xor(a1, off);
        a2v += __shfl_xor(a2v, off);
    }
    // self loop
    a0  += sx[d * 3 + 0];
    a1  += sx[d * 3 + 1];
    a2v += sx[d * 3 + 2];
    float r = dis[d];
    float v = r * (a0 * W1[lane] + a1 * W1[64 + lane] + a2v * W1[128 + lane]) + b1[lane];
    v = (v > 0.f) ? v : expm1f(v);
    s1[(size_t)d * 64 + lane] = r * v;  // pre-scale for next aggregation
}

// ---- layer 2 aggregation: a2[d] = dis[d]*(sum_nbr s1[s] + s1[d]) ----
__global__ void agg64_kernel(const float* __restrict__ s1, const int* __restrict__ row_ptr,
                             const int* __restrict__ col, const float* __restrict__ dis,
                             float* __restrict__ a2, int N) {
    int wave = (blockIdx.x * blockDim.x + threadIdx.x) >> 6;
    int lane = threadIdx.x & 63;
    if (wave >= N) return;
    int d = wave;
    int start = row_ptr[d], end = row_ptr[d + 1];
    float acc0 = s1[(size_t)d * 64 + lane];  // self loop
    float acc1 = 0.f, acc2 = 0.f, acc3 = 0.f;
    int i = start;
    for (; i + 3 < end; i += 4) {
        int s0 = col[i], s1i = col[i + 1], s2 = col[i + 2], s3 = col[i + 3];
        acc0 += s1[(size_t)s0  * 64 + lane];
        acc1 += s1[(size_t)s1i * 64 + lane];
        acc2 += s1[(size_t)s2  * 64 + lane];
        acc3 += s1[(size_t)s3  * 64 + lane];
    }
    for (; i < end; ++i) acc0 += s1[(size_t)col[i] * 64 + lane];
    a2[(size_t)d * 64 + lane] = dis[d] * ((acc0 + acc1) + (acc2 + acc3));
}

// ---- fused head: out = softmax(elu(elu(a2@W2+b2)@Wm1+bm1)@Wm2+bm2) ----
// Register-light: max 4 accumulators per thread, partial unroll only.
__global__ __launch_bounds__(256) void head_kernel(const float* __restrict__ a2,
    const float* __restrict__ W2g, const float* __restrict__ b2g,
    const float* __restrict__ Wm1g, const float* __restrict__ bm1g,
    const float* __restrict__ Wm2g, const float* __restrict__ bm2g,
    float* __restrict__ out, int N) {
    __shared__ float W2s[64 * 64];     // [k][f] 16 KB
    __shared__ float Wm1s[64 * 128];   // [f][j] 32 KB
    __shared__ float b2s[64];
    __shared__ float bm1s[128];
    __shared__ float bm2s[16];
    __shared__ float at[64 * NTP];     // a2 tile transposed [k][n]
    __shared__ float tt[64 * NTP];     // h2 tile [f][n]
    __shared__ float mt[NT * 129];     // m tile [n][j] padded
    __shared__ float ot[NT * 16];      // logits [n][c]
    int tid = threadIdx.x;
    for (int i = tid; i < 64 * 64;  i += 256) W2s[i]  = W2g[i];
    for (int i = tid; i < 64 * 128; i += 256) Wm1s[i] = Wm1g[i];
    if (tid < 64)  b2s[tid]  = b2g[tid];
    if (tid < 128) bm1s[tid] = bm1g[tid];
    if (tid < 16)  bm2s[tid] = (tid < 15) ? bm2g[tid] : 0.f;
    __syncthreads();

    int nTiles = (N + NT - 1) / NT;
    int f  = tid & 63;            // stage A output feature / stage B j-low
    int n0 = (tid >> 6) * 4;      // 4-node group for stages A/B
    int cc16 = tid & 15;          // stage C class
    int cn   = tid >> 4;          // stage C node (0..15)
    int coff = (cc16 < 15) ? cc16 : 0;

    for (int tile = blockIdx.x; tile < nTiles; tile += gridDim.x) {
        int base = tile * NT;
        // ---- stage a2 tile transposed ----
        {
            int n = tid >> 6, k = tid & 63;
#pragma unroll
            for (int g = 0; g < 4; ++g) {
                int nn = n * 4 + g;
                int node = base + nn; if (node >= N) node = N - 1;
                at[k * NTP + nn] = a2[(size_t)node * 64 + k];
            }
        }
        __syncthreads();
        // ---- stage A: h2 = elu(a2@W2+b2), 64 f x 16 n ----
        {
            float bb = b2s[f];
            float acc0 = bb, acc1 = bb, acc2 = bb, acc3 = bb;
#pragma unroll 4
            for (int k = 0; k < 64; ++k) {
                float w = W2s[k * 64 + f];
                const float* a = &at[k * NTP + n0];
                acc0 = fmaf(w, a[0], acc0);
                acc1 = fmaf(w, a[1], acc1);
                acc2 = fmaf(w, a[2], acc2);
                acc3 = fmaf(w, a[3], acc3);
            }
            float* t = &tt[f * NTP + n0];
            t[0] = (acc0 > 0.f) ? acc0 : expm1f(acc0);
            t[1] = (acc1 > 0.f) ? acc1 : expm1f(acc1);
            t[2] = (acc2 > 0.f) ? acc2 : expm1f(acc2);
            t[3] = (acc3 > 0.f) ? acc3 : expm1f(acc3);
        }
        __syncthreads();
        // ---- stage B: m = elu(h2@Wm1+bm1), 128 j x 16 n, two j-half passes ----
#pragma unroll
        for (int pass = 0; pass < 2; ++pass) {
            int j = f + pass * 64;
            float bb = bm1s[j];
            float acc0 = bb, acc1 = bb, acc2 = bb, acc3 = bb;
#pragma unroll 4
            for (int ff = 0; ff < 64; ++ff) {
                float w = Wm1s[ff * 128 + j];
                const float* t = &tt[ff * NTP + n0];
                acc0 = fmaf(w, t[0], acc0);
                acc1 = fmaf(w, t[1], acc1);
                acc2 = fmaf(w, t[2], acc2);
                acc3 = fmaf(w, t[3], acc3);
            }
            mt[(n0 + 0) * 129 + j] = (acc0 > 0.f) ? acc0 : expm1f(acc0);
            mt[(n0 + 1) * 129 + j] = (acc1 > 0.f) ? acc1 : expm1f(acc1);
            mt[(n0 + 2) * 129 + j] = (acc2 > 0.f) ? acc2 : expm1f(acc2);
            mt[(n0 + 3) * 129 + j] = (acc3 > 0.f) ? acc3 : expm1f(acc3);
        }
        __syncthreads();
        // ---- stage C: logits = m@Wm2+bm2, 15 c x 16 n (c=15 lane idle) ----
        {
            float acc = bm2s[cc16];
#pragma unroll 4
            for (int j = 0; j < 128; ++j) {
                acc = fmaf(mt[cn * 129 + j], Wm2g[j * 15 + coff], acc);
            }
            if (cc16 < 15) ot[cn * 16 + cc16] = acc;
        }
        __syncthreads();
        // ---- softmax over 15 classes, write out ----
        {
            int node = base + cn;
            if (cc16 < 15 && node < N) {
                float mx = -1e30f;
#pragma unroll
                for (int c2 = 0; c2 < 15; ++c2) mx = fmaxf(mx, ot[cn * 16 + c2]);
                float ssum = 0.f;
#pragma unroll
                for (int c2 = 0; c2 < 15; ++c2) ssum += __expf(ot[cn * 16 + c2] - mx);
                out[(size_t)node * 15 + cc16] = __expf(ot[cn * 16 + cc16] - mx) / ssum;
            }
        }
        __syncthreads();
    }
}

extern "C" void kernel_launch(void* const* d_in, const int* in_sizes, int n_in,
                              void* d_out, int out_size, void* d_ws, size_t ws_size,
                              hipStream_t stream) {
    const float* x   = (const float*)d_in[0];
    const int*   ei  = (const int*)d_in[1];
    const float* W1  = (const float*)d_in[2];
    const float* b1  = (const float*)d_in[3];
    const float* W2  = (const float*)d_in[4];
    const float* b2  = (const float*)d_in[5];
    const float* Wm1 = (const float*)d_in[6];
    const float* bm1 = (const float*)d_in[7];
    const float* Wm2 = (const float*)d_in[8];
    const float* bm2 = (const float*)d_in[9];
    float* out = (float*)d_out;

    int N = in_sizes[0] / 3;
    int E = in_sizes[1] / 2;
    const int* src = ei;
    const int* dst = ei + E;

    uintptr_t p = (uintptr_t)d_ws;
    auto carve = [&](size_t bytes) -> void* {
        p = (p + 255) & ~(uintptr_t)255;
        void* r = (void*)p;
        p += bytes;
        return r;
    };
    int*   deg     = (int*)carve((size_t)N * 4);
    int*   cursor  = (int*)carve((size_t)N * 4);
    int*   row_ptr = (int*)carve((size_t)(N + 1) * 4);
    int*   bsum    = (int*)carve(256);
    float* dis     = (float*)carve((size_t)N * 4);
    float* sx      = (float*)carve((size_t)N * 12);
    int*   col     = (int*)carve((size_t)E * 4);
    float* s1      = (float*)carve((size_t)N * 64 * 4);
    float* a2      = (float*)carve((size_t)N * 64 * 4);

    int eBlocks = (E + 255) / 256;
    int nBlocks = (N + 255) / 256;
    int NB = (N + 2047) / 2048;
    int waveBlocks = (N + 3) / 4;  // 4 waves (nodes) per 256-thread block

    hipMemsetAsync(deg,    0, (size_t)N * 4, stream);
    hipMemsetAsync(cursor, 0, (size_t)N * 4, stream);

    deg_kernel<<<eBlocks, 256, 0, stream>>>(dst, deg, E);
    dis_kernel<<<nBlocks, 256, 0, stream>>>(deg, x, dis, sx, N);
    scan1_kernel<<<NB, 256, 0, stream>>>(deg, bsum, N);
    scan2_kernel<<<1, 64, 0, stream>>>(bsum, row_ptr, NB, N);
    scan3_kernel<<<NB, 256, 0, stream>>>(deg, bsum, row_ptr, N);
    fill_kernel<<<eBlocks, 256, 0, stream>>>(src, dst, row_ptr, cursor, col, E);
    agg3_kernel<<<waveBlocks, 256, 0, stream>>>(sx, row_ptr, col, dis, W1, b1, s1, N);
    agg64_kernel<<<waveBlocks, 256, 0, stream>>>(s1, row_ptr, col, dis, a2, N);
    head_kernel<<<512, 256, 0, stream>>>(a2, W2, b2, Wm1, bm1, Wm2, bm2, out, N);
}